// Round 15
// baseline (569.820 us; speedup 1.0000x reference)
//
#include <hip/hip_runtime.h>
#include <math.h>

#define NN 50000
#define NE 600000
#define ADIM 75
#define HID 128
#define NLAYERS 4
#define NGRAPHS 128
#define BN_EPS 1e-5f
#define NNP 50048   // NN padded to 128-node blocks (50048 = 391*128)
#define NB128 (NNP / 128)   // 391 node-blocks

typedef short bhalf8 __attribute__((ext_vector_type(8)));
typedef unsigned short ushort8v __attribute__((ext_vector_type(8)));
typedef float floatx4 __attribute__((ext_vector_type(4)));

__device__ __forceinline__ float sigm(float v) { return 1.0f / (1.0f + __expf(-v)); }
__device__ __forceinline__ float tanh_f(float v) {
    return 1.0f - 2.0f / (__expf(2.0f * v) + 1.0f);
}

// fp32 -> bf16 with round-to-nearest-even
__device__ __forceinline__ unsigned short f2bf(float f) {
    unsigned u = __builtin_bit_cast(unsigned, f);
    u = (u + 0x7FFFu + ((u >> 16) & 1u)) >> 16;
    return (unsigned short)u;
}
__device__ __forceinline__ float bf2f(unsigned short h) {
    return __builtin_bit_cast(float, ((unsigned)h) << 16);
}

// async global->LDS, 16B per lane. LDS dest is wave-uniform base + lane*16;
// global src is per-lane (must already include +lane*16).
__device__ __forceinline__ void gl2lds16(const void* g, void* l) {
    __builtin_amdgcn_global_load_lds(
        (const __attribute__((address_space(1))) unsigned int*)g,
        (__attribute__((address_space(3))) unsigned int*)l, 16, 0, 0);
}

// ---------------------------------------------------------------------------
// k_prep: merged precompute (range-split by blockIdx):
//   [0,768):      Whh -> whhb bf16 MFMA B-fragments
//   [768,5456):   nf [NN x 75] fp32 -> nfb [NNP x 96] bf16 (K zero-padded)
//   [5456,5504):  embW [128 x 75] -> web bf16 B-frags (K padded 75->96)
// ---------------------------------------------------------------------------
#define PREP_G (768 + 4688 + 48)
__global__ __launch_bounds__(256) void k_prep(
    const float* __restrict__ Whh, unsigned short* __restrict__ whhb,
    const float* __restrict__ nf, unsigned short* __restrict__ nfb,
    const float* __restrict__ W, unsigned short* __restrict__ web)
{
    const int b = blockIdx.x;
    if (b < 768) {
        int e = b * 256 + threadIdx.x;           // < 196608 = 4*49152
        int l = e / 49152, em = e - l * 49152;
        int j = em & 7, n = (em >> 3) & 15, quad = (em >> 7) & 3;
        int kb = (em >> 9) & 3, tc = (em >> 11) & 7, g = (em >> 14);
        int row = g * 128 + tc * 16 + n;
        int kk = kb * 32 + quad * 8 + j;
        whhb[e] = f2bf(Whh[(size_t)l * 49152 + row * 128 + kk]);
    } else if (b < 768 + 4688) {
        int e = (b - 768) * 256 + threadIdx.x;   // (n, k4): 50000*24
        if (e >= NN * 24) return;
        int n = e / 24, k4 = e - n * 24;
        ushort4 o;
        int k = k4 * 4;
        o.x = (k + 0 < ADIM) ? f2bf(nf[(size_t)n * ADIM + k + 0]) : 0;
        o.y = (k + 1 < ADIM) ? f2bf(nf[(size_t)n * ADIM + k + 1]) : 0;
        o.z = (k + 2 < ADIM) ? f2bf(nf[(size_t)n * ADIM + k + 2]) : 0;
        o.w = (k + 3 < ADIM) ? f2bf(nf[(size_t)n * ADIM + k + 3]) : 0;
        ((ushort4*)nfb)[(size_t)n * 24 + k4] = o;
    } else {
        int e = (b - 5456) * 256 + threadIdx.x;  // 0..12287
        int j = e & 7, n = (e >> 3) & 15, quad = (e >> 7) & 3;
        int kb = (e >> 9) % 3, tc = e / 1536;
        int row = tc * 16 + n;
        int kk = kb * 32 + quad * 8 + j;
        web[e] = (kk < ADIM) ? f2bf(W[row * ADIM + kk]) : 0;
    }
}

// ---------------------------------------------------------------------------
// MFMA embedding — 512 threads (8 waves), 128 nodes/block, grid 391.
// y stored as BF16 (y16); BN partials from rounded value.
// ---------------------------------------------------------------------------
__global__ __launch_bounds__(512) void k_embed_m(
    const unsigned short* __restrict__ nfb, const unsigned short* __restrict__ web,
    const float* __restrict__ b, unsigned short* __restrict__ y16,
    float* __restrict__ bnsum)
{
    __shared__ __align__(16) unsigned short wbe[12288];    // 24 KB emb B-frags
    __shared__ float sred[1024], sred2[1024];              // 8 KB BN partials
    const int t = threadIdx.x;
    const int wave = t >> 6, lane = t & 63;
    const int col = lane & 15, quad = (lane >> 4) & 3;
    const int node0 = blockIdx.x * 128;

    // stage web: 24576 B = 8 waves x 3 KB, identity copy
    {
        const char* gsrc = (const char*)web + wave * 3072 + lane * 16;
        char* ldst = (char*)wbe + wave * 3072;
#pragma unroll
        for (int i = 0; i < 3; i++)
            gl2lds16(gsrc + i * 1024, ldst + i * 1024);
    }

    const int anode = node0 + wave * 16 + col;
    bhalf8 afN[3];
#pragma unroll
    for (int kb = 0; kb < 3; kb++)
        afN[kb] = *(const bhalf8*)&nfb[(size_t)anode * 96 + kb * 32 + quad * 8];

    floatx4 acc[8];
#pragma unroll
    for (int tc = 0; tc < 8; tc++) {
        float bv = b[tc * 16 + col];
        acc[tc] = (floatx4){bv, bv, bv, bv};
    }
    __syncthreads();   // drains vmcnt -> wbe staged

#pragma unroll
    for (int tc = 0; tc < 8; tc++) {
        bhalf8 bfr[3];
#pragma unroll
        for (int kb = 0; kb < 3; kb++)
            bfr[kb] = *(const bhalf8*)&wbe[((tc * 3 + kb) * 64 + lane) * 8];
#pragma unroll
        for (int kb = 0; kb < 3; kb++)
            acc[tc] = __builtin_amdgcn_mfma_f32_16x16x32_bf16(afN[kb], bfr[kb], acc[tc], 0, 0, 0);
    }

    // relu + bf16 y stores + register BN partials (from rounded value)
    float ps[8], ps2[8];
#pragma unroll
    for (int tc = 0; tc < 8; tc++) {
        ps[tc] = 0.f; ps2[tc] = 0.f;
#pragma unroll
        for (int e = 0; e < 4; e++) {
            float v = fmaxf(acc[tc][e], 0.0f);
            int nd = node0 + wave * 16 + quad * 4 + e;
            if (nd < NN) {
                unsigned short vb = f2bf(v);
                float vr = bf2f(vb);
                y16[(size_t)nd * HID + tc * 16 + col] = vb;
                ps[tc] += vr; ps2[tc] += vr * vr;
            }
        }
    }
#pragma unroll
    for (int tc = 0; tc < 8; tc++) {
        ps[tc]  += __shfl_xor(ps[tc], 16);  ps2[tc] += __shfl_xor(ps2[tc], 16);
        ps[tc]  += __shfl_xor(ps[tc], 32);  ps2[tc] += __shfl_xor(ps2[tc], 32);
    }
    if (quad == 0) {
#pragma unroll
        for (int tc = 0; tc < 8; tc++) {
            sred[wave * 128 + tc * 16 + col]  = ps[tc];
            sred2[wave * 128 + tc * 16 + col] = ps2[tc];
        }
    }
    __syncthreads();
    if (t < 128) {
        float s = 0.f, s2 = 0.f;
#pragma unroll
        for (int w = 0; w < 8; w++) { s += sred[w * 128 + t]; s2 += sred2[w * 128 + t]; }
        unsafeAtomicAdd(&bnsum[t], s);
        unsafeAtomicAdd(&bnsum[128 + t], s2);
    }
}

// ---------------------------------------------------------------------------
// Fused BN-finalize + BN-apply + bf16 mirror + attention projections.
// R27: vectorized 16 B/lane; 16 lanes/node, 16 nodes/block, grid 3125.
// ---------------------------------------------------------------------------
__global__ __launch_bounds__(256) void k_bnx(
    const unsigned short* __restrict__ y16, const float* __restrict__ bnsum,
    const float* __restrict__ g, const float* __restrict__ beta,
    const float* __restrict__ attW, int do_proj,
    unsigned short* __restrict__ xb,
    float* __restrict__ as_, float* __restrict__ ad_)
{
    const int t = threadIdx.x;
    const int n = blockIdx.x * 16 + (t >> 4);   // 16 nodes/block (3125*16=NN)
    const int fl = t & 15;                      // feature chunk fl*8..fl*8+7
    const int f0 = fl * 8;
    const float inv = 1.0f / (float)NN;

    // per-lane BN scale/shift for 8 features (all inputs L2-resident)
    float sc[8], sh[8];
#pragma unroll
    for (int j4 = 0; j4 < 2; j4++) {
        float4 s  = *(const float4*)&bnsum[f0 + j4 * 4];
        float4 s2 = *(const float4*)&bnsum[128 + f0 + j4 * 4];
        float4 gg = *(const float4*)&g[f0 + j4 * 4];
        float4 bb = *(const float4*)&beta[f0 + j4 * 4];
        const float* sp = (const float*)&s;
        const float* s2p = (const float*)&s2;
        const float* gp = (const float*)&gg;
        const float* bp = (const float*)&bb;
#pragma unroll
        for (int j = 0; j < 4; j++) {
            float m = sp[j] * inv;
            float vv = s2p[j] * inv - m * m;
            float scv = gp[j] * rsqrtf(vv + BN_EPS);
            sc[j4 * 4 + j] = scv;
            sh[j4 * 4 + j] = bp[j] - m * scv;
        }
    }

    ushort8v yv = *(const ushort8v*)&y16[(size_t)n * HID + f0];
    float xv[8];
    ushort8v o;
#pragma unroll
    for (int j = 0; j < 8; j++) {
        xv[j] = bf2f(yv[j]) * sc[j] + sh[j];
        o[j] = f2bf(xv[j]);
    }
    *(ushort8v*)&xb[(size_t)n * HID + f0] = o;

    if (do_proj) {
        float pas = 0.f, pad = 0.f;
#pragma unroll
        for (int j4 = 0; j4 < 2; j4++) {
            float4 ws = *(const float4*)&attW[f0 + j4 * 4];
            float4 wd = *(const float4*)&attW[128 + f0 + j4 * 4];
            const float* wsp = (const float*)&ws;
            const float* wdp = (const float*)&wd;
#pragma unroll
            for (int j = 0; j < 4; j++) {
                pas += xv[j4 * 4 + j] * wsp[j];
                pad += xv[j4 * 4 + j] * wdp[j];
            }
        }
#pragma unroll
        for (int msk = 8; msk >= 1; msk >>= 1) {
            pas += __shfl_xor(pas, msk);
            pad += __shfl_xor(pad, msk);
        }
        if (fl == 0) { as_[n] = pas; ad_[n] = pad; }
    }
}

// ---------------------------------------------------------------------------
// Combined-weight precompute + DIRECT fragment write (each block owns one
// full row of Wc = Wih[l] @ Wm[l] -> emits that row's bf16 MFMA B-frags;
// fp32 Wc never materialized). Also bmih[l] = Wih[l] @ bm[l].
// ---------------------------------------------------------------------------
__global__ __launch_bounds__(128) void k_wc(
    const float* __restrict__ Wih, const float* __restrict__ Wm,
    const float* __restrict__ bm, unsigned short* __restrict__ wcb,
    float* __restrict__ bmih)
{
    __shared__ float sw[128];
    __shared__ float red[128];
    const int b = blockIdx.x;
    const int l = b / 384, r = b - l * 384;      // r = row within 384x128
    const int t = threadIdx.x;
    const float* wihrow = Wih + ((size_t)l * 384 + r) * 128;
    sw[t] = wihrow[t];
    __syncthreads();
    const float* wm = Wm + (size_t)l * 128 * 128;
    float acc = 0.f;
#pragma unroll 8
    for (int k = 0; k < 128; k++) acc += sw[k] * wm[k * 128 + t];
    // fragment write: row -> (g,tc,n), col t -> (kb,quad,j)
    {
        int g = r >> 7, rowin = r & 127;
        int tc = rowin >> 4, n = rowin & 15;
        int kb = t >> 5, quad = (t >> 3) & 3, j = t & 7;
        wcb[(size_t)l * 49152 + (g << 14) + (tc << 11) + (kb << 9) +
            (quad << 7) + (n << 3) + j] = f2bf(acc);
    }
    red[t] = sw[t] * bm[l * 128 + t];
    __syncthreads();
#pragma unroll
    for (int off = 64; off >= 1; off >>= 1) {
        if (t < off) red[t] += red[t + off];
        __syncthreads();
    }
    if (t == 0) bmih[l * 384 + r] = red[0];
}

// ---------------------------------------------------------------------------
// CSR build: histogram, 3-kernel device-wide scan, scatter
// ---------------------------------------------------------------------------
__global__ __launch_bounds__(256) void k_count(const int* __restrict__ dst, int* __restrict__ cnt)
{
    int e = blockIdx.x * 256 + threadIdx.x;
    if (e < NE) atomicAdd(&cnt[dst[e]], 1);
}

#define SCAN_B 512
#define SCAN_G 98          // 98*512 = 50176 >= 50000

__global__ __launch_bounds__(SCAN_B) void k_scan1(
    const int* __restrict__ cnt, int* __restrict__ rowptr, int* __restrict__ bsum)
{
    __shared__ int s[SCAN_B];
    const int t = threadIdx.x;
    const int i = blockIdx.x * SCAN_B + t;
    int v = (i < NN) ? cnt[i] : 0;
    s[t] = v;
    __syncthreads();
#pragma unroll
    for (int off = 1; off < SCAN_B; off <<= 1) {
        int u = (t >= off) ? s[t - off] : 0;
        __syncthreads();
        s[t] += u;
        __syncthreads();
    }
    if (i < NN) rowptr[i] = s[t] - v;        // local exclusive
    if (t == SCAN_B - 1) bsum[blockIdx.x] = s[t];
}

__global__ __launch_bounds__(128) void k_scan2(int* __restrict__ bsum, int* __restrict__ rowptr)
{
    __shared__ int s[128];
    const int t = threadIdx.x;
    int v = (t < SCAN_G) ? bsum[t] : 0;
    s[t] = v;
    __syncthreads();
#pragma unroll
    for (int off = 1; off < 128; off <<= 1) {
        int u = (t >= off) ? s[t - off] : 0;
        __syncthreads();
        s[t] += u;
        __syncthreads();
    }
    if (t < SCAN_G) bsum[t] = s[t] - v;      // exclusive offsets
    if (t == 127) rowptr[NN] = s[127];       // grand total (= NE)
}

__global__ __launch_bounds__(SCAN_B) void k_scan3(
    int* __restrict__ rowptr, const int* __restrict__ bsum, int* __restrict__ wptr)
{
    const int i = blockIdx.x * SCAN_B + threadIdx.x;
    if (i < NN) {
        int v = rowptr[i] + bsum[blockIdx.x];
        rowptr[i] = v;
        wptr[i] = v;
    }
}

__global__ __launch_bounds__(256) void k_scatter(
    const int* __restrict__ src, const int* __restrict__ dst,
    int* __restrict__ wptr, int* __restrict__ ssrc)
{
    int e = blockIdx.x * 256 + threadIdx.x;
    if (e < NE) {
        int d = dst[e];
        int pos = atomicAdd(&wptr[d], 1);
        ssrc[pos] = src[e];
    }
}

// ---------------------------------------------------------------------------
// Gather-aggregate — R28: row-load pipelining on R26's 16 B/lane form.
// ids prefetched one batch ahead; row loads one batch ahead; ~1 serial
// load-drain per node at deg~12. VGPR ~100 (same occupancy bucket).
// R22: own high-TLP geometry (6250 blocks). R24: don't grow live state.
// ---------------------------------------------------------------------------
__global__ __launch_bounds__(256) void k_gather(
    const int* __restrict__ rowptr, const int* __restrict__ ssrc,
    const unsigned short* __restrict__ xb, const float* __restrict__ as_,
    const float* __restrict__ ad_, const float* __restrict__ attb, int l,
    unsigned short* __restrict__ aggxb, float* __restrict__ sumatt)
{
    const int t = threadIdx.x;
    const int n = blockIdx.x * 8 + (t >> 5);
    const int lane32 = t & 31;
    const int sub = lane32 >> 4;          // which half of the edge batch
    const int fl = lane32 & 15;           // feature chunk: fl*8 .. fl*8+7
    const int r0 = rowptr[n], r1 = rowptr[n + 1];
    const float adv = ad_[n] + attb[l];
    float acc[8] = {0.f, 0.f, 0.f, 0.f, 0.f, 0.f, 0.f, 0.f};
    float satt = 0.f;

    int idsB[8];                          // ids for batch k+1 (arrived)
    ushort8v vA[4]; float aA[4];          // rows for batch k (in flight/arrived)
    if (r0 < r1) {
        int idsA[8];
#pragma unroll
        for (int k = 0; k < 8; k++) {
            int i0 = r0 + k;     if (i0 >= r1) i0 = r1 - 1;
            int i1 = r0 + 8 + k; if (i1 >= r1) i1 = r1 - 1;
            idsA[k] = ssrc[i0];
            idsB[k] = ssrc[i1];
        }
#pragma unroll
        for (int k = 0; k < 4; k++) {
            const int e = k * 2 + sub;
            vA[k] = *(const ushort8v*)&xb[(size_t)idsA[e] * 128 + fl * 8];
            aA[k] = as_[idsA[e]];
        }
    }
    for (int base = r0; base < r1; base += 8) {
        int idsN[8];                      // prefetch ids for batch k+2
        if (base + 16 < r1) {
#pragma unroll
            for (int k = 0; k < 8; k++) {
                int idx = base + 16 + k; if (idx >= r1) idx = r1 - 1;
                idsN[k] = ssrc[idx];
            }
        }
        ushort8v vN[4]; float aN[4];      // issue rows for batch k+1
        if (base + 8 < r1) {
#pragma unroll
            for (int k = 0; k < 4; k++) {
                const int e = k * 2 + sub;
                vN[k] = *(const ushort8v*)&xb[(size_t)idsB[e] * 128 + fl * 8];
                aN[k] = as_[idsB[e]];
            }
        }
        // accumulate batch k (vA/aA already in flight since previous iter)
#pragma unroll
        for (int k = 0; k < 4; k++) {
            const int e = k * 2 + sub;
            if (base + e < r1) {
                float att = sigm(aA[k] + adv);
#pragma unroll
                for (int j = 0; j < 8; j++)
                    acc[j] += bf2f(vA[k][j]) * att;
                if (fl == 0) satt += att;
            }
        }
        // rotate
#pragma unroll
        for (int k = 0; k < 4; k++) { vA[k] = vN[k]; aA[k] = aN[k]; }
#pragma unroll
        for (int k = 0; k < 8; k++) idsB[k] = idsN[k];
    }
    // combine the two edge-subgroups (lane ^ 16 stays within the node group)
#pragma unroll
    for (int j = 0; j < 8; j++) acc[j] += __shfl_xor(acc[j], 16);
    satt += __shfl_xor(satt, 16);
    if (lane32 < 16) {
        ushort8v o;
#pragma unroll
        for (int j = 0; j < 8; j++) o[j] = f2bf(acc[j]);
        *(ushort8v*)&aggxb[(size_t)n * 128 + fl * 8] = o;
    }
    if (lane32 == 0) sumatt[n] = satt;
}

// ---------------------------------------------------------------------------
// MFMA GRU — R20 geometry (512 thr / 8 waves, 128 nodes/block, grid 391).
// R29: epilogue xv reads via LDS — after the final MMGL (last wbuf reader),
// the block's own 32 KB xb tile is re-staged into wbuf with gl2lds16
// (contiguous identity copy); the z=sigm pass overlaps the stage drain;
// xv then comes from LDS. Replaces 16k quarter-coalesced 2 B global loads
// per block (Guideline-13 violation on the post-MFMA critical path) with
// 2k vectorized async loads. Everything else: R16-R24 established that
// schedule/occupancy/traffic are NOT the lever (~50 us invariant).
// R19: no extra node-tiles/wave. R22: no gather fusion. R11/R13: no
// occupancy forcing. R8: no column split.
// ---------------------------------------------------------------------------
#define STAGE_W(SRC)                                                          \
    {                                                                         \
        const char* gsrc = (const char*)(SRC) + wave * 4096 + lane * 16;      \
        char* ldst = (char*)wbuf + wave * 4096;                               \
        _Pragma("unroll")                                                     \
        for (int i = 0; i < 4; i++)                                           \
            gl2lds16(gsrc + i * 1024, ldst + i * 1024);                       \
    }

#define MMGL(AF, ACC)                                                         \
    _Pragma("unroll")                                                         \
    for (int tc = 0; tc < 8; tc++) {                                          \
        bhalf8 bfr[4];                                                        \
        _Pragma("unroll")                                                     \
        for (int kb = 0; kb < 4; kb++)                                        \
            bfr[kb] = *(const bhalf8*)&wbuf[((tc * 4 + kb) * 64 + lane) * 8]; \
        _Pragma("unroll")                                                     \
        for (int kb = 0; kb < 4; kb++)                                        \
            ACC[tc] = __builtin_amdgcn_mfma_f32_16x16x32_bf16(AF[kb], bfr[kb], ACC[tc], 0, 0, 0); \
    }

__global__ __launch_bounds__(512) void k_gru(
    const unsigned short* __restrict__ aggxb, const float* __restrict__ sumatt,
    const unsigned short* __restrict__ xb,
    const unsigned short* __restrict__ wcb, const float* __restrict__ bmih,
    const float* __restrict__ bih,
    const unsigned short* __restrict__ whhb, const float* __restrict__ bhh,
    unsigned short* __restrict__ y16, float* __restrict__ bnsum)
{
    __shared__ __align__(16) unsigned short wbuf[16384];   // 32 KB stage (weights, then xb tile)
    __shared__ float sred[1024], sred2[1024];              // 8 KB BN partials
    const int t = threadIdx.x;
    const int wave = t >> 6, lane = t & 63;
    const int col = lane & 15, quad = (lane >> 4) & 3;
    const int node0 = blockIdx.x * 128;

    STAGE_W(wcb + 0 * 16384);    // issue gate-r Wc stage before A loads

    const int anode = node0 + wave * 16 + col;
    bhalf8 afA[4], afX[4];
#pragma unroll
    for (int kb = 0; kb < 4; kb++) {
        afA[kb] = *(const bhalf8*)&aggxb[(size_t)anode * HID + kb * 32 + quad * 8];
        afX[kb] = *(const bhalf8*)&xb[(size_t)anode * HID + kb * 32 + quad * 8];
    }
    float sa[4];
#pragma unroll
    for (int e = 0; e < 4; e++) sa[e] = sumatt[node0 + wave * 16 + quad * 4 + e];

    floatx4 accR[8], accN[8];

    // ===== gate r: merged accumulator (gi+gh) =====
#pragma unroll
    for (int tc = 0; tc < 8; tc++) {
        int f = 0 * 128 + tc * 16 + col;
        float b0 = bih[f] + bhh[f], bm = bmih[f];
        accR[tc] = (floatx4){b0 + sa[0] * bm, b0 + sa[1] * bm, b0 + sa[2] * bm, b0 + sa[3] * bm};
    }
    __syncthreads();                 // wcb[r] staged (drains vmcnt)
    MMGL(afA, accR);
    __syncthreads();                 // all waves done reading
    STAGE_W(whhb + 0 * 16384);
    __syncthreads();
    MMGL(afX, accR);
    __syncthreads();
    STAGE_W(whhb + 2 * 16384);       // prefetch gate-n Whh; sigm overlaps
#pragma unroll
    for (int tc = 0; tc < 8; tc++)
#pragma unroll
        for (int e = 0; e < 4; e++)
            accR[tc][e] = sigm(accR[tc][e]);          // accR now holds r

    // ===== gate n: acc = afX@Whh + bh; acc = r*acc + bi + sa*bm; acc += afA@Wc =====
#pragma unroll
    for (int tc = 0; tc < 8; tc++) {
        float bh = bhh[2 * 128 + tc * 16 + col];
        accN[tc] = (floatx4){bh, bh, bh, bh};
    }
    __syncthreads();
    MMGL(afX, accN);
    __syncthreads();
    STAGE_W(wcb + 2 * 16384);        // prefetch gate-n Wc; r-merge overlaps
#pragma unroll
    for (int tc = 0; tc < 8; tc++) {
        int f = 2 * 128 + tc * 16 + col;
        float bi = bih[f], bm = bmih[f];
#pragma unroll
        for (int e = 0; e < 4; e++)
            accN[tc][e] = accR[tc][e] * accN[tc][e] + bi + sa[e] * bm;
    }
    __syncthreads();
    MMGL(afA, accN);
    __syncthreads();
    STAGE_W(wcb + 1 * 16384);        // prefetch gate-z Wc; tanh overlaps
#pragma unroll
    for (int tc = 0; tc < 8; tc++)
#pragma unroll
        for (int e = 0; e < 4; e++)
            accN[tc][e] = tanh_f(accN[tc][e]);        // accN now holds n

    // ===== gate z: merged accumulator (reuse accR) =====
#pragma unroll
    for (int tc = 0; tc < 8; tc++) {
        int f = 1 * 128 + tc * 16 + col;
        float b0 = bih[f] + bhh[f], bm = bmih[f];
        accR[tc] = (floatx4){b0 + sa[0] * bm, b0 + sa[1] * bm, b0 + sa[2] * bm, b0 + sa[3] * bm};
    }
    __syncthreads();
    MMGL(afA, accR);
    __syncthreads();
    STAGE_W(whhb + 1 * 16384);
    __syncthreads();
    MMGL(afX, accR);

    // ===== R29: re-stage own xb tile (32 KB contiguous) into wbuf =====
    __syncthreads();                 // all waves done with whhb[z] in wbuf
    STAGE_W(xb + (size_t)node0 * HID);
    // overlap stage drain with z = sigm(accR)
#pragma unroll
    for (int tc = 0; tc < 8; tc++)
#pragma unroll
        for (int e = 0; e < 4; e++)
            accR[tc][e] = sigm(accR[tc][e]);          // accR now holds z
    __syncthreads();                 // xb tile staged (drains vmcnt)

    // ===== h = (1-z)*n + z*x (x from LDS); bf16 y stores; BN partials =====
    float ps[8], ps2[8];
#pragma unroll
    for (int tc = 0; tc < 8; tc++) {
        ps[tc] = 0.f; ps2[tc] = 0.f;
#pragma unroll
        for (int e = 0; e < 4; e++) {
            float z = accR[tc][e];
            int nl = wave * 16 + quad * 4 + e;
            int nd = node0 + nl;
            float xv = bf2f(wbuf[nl * HID + tc * 16 + col]);
            float h = (1.0f - z) * accN[tc][e] + z * xv;
            if (nd < NN) {
                unsigned short hb = f2bf(h);
                float hr = bf2f(hb);
                y16[(size_t)nd * HID + tc * 16 + col] = hb;
                ps[tc] += hr; ps2[tc] += hr * hr;
            }
        }
    }
#pragma unroll
    for (int tc = 0; tc < 8; tc++) {
        ps[tc]  += __shfl_xor(ps[tc], 16);  ps2[tc] += __shfl_xor(ps2[tc], 16);
        ps[tc]  += __shfl_xor(ps[tc], 32);  ps2[tc] += __shfl_xor(ps2[tc], 32);
    }
    if (quad == 0) {
#pragma unroll
        for (int tc = 0; tc < 8; tc++) {
            sred[wave * 128 + tc * 16 + col]  = ps[tc];
            sred2[wave * 128 + tc * 16 + col] = ps2[tc];
        }
    }
    __syncthreads();
    if (t < 128) {
        float s = 0.f, s2 = 0.f;
#pragma unroll
        for (int w = 0; w < 8; w++) { s += sred[w * 128 + t]; s2 += sred2[w * 128 + t]; }
        unsafeAtomicAdd(&bnsum[t], s);
        unsafeAtomicAdd(&bnsum[128 + t], s2);
    }
}

// ---------------------------------------------------------------------------
// Segmented sum-pool over bf16 xb (batch_idx is SORTED).
// R28: vectorized 16 B/lane; 16 node-slots x 16 feature-chunks per block.
// ---------------------------------------------------------------------------
__global__ __launch_bounds__(256) void k_pool(
    const unsigned short* __restrict__ xb, const int* __restrict__ batch,
    float* __restrict__ gr)
{
    __shared__ int sb[256];
    const int t = threadIdx.x;
    const int nb = blockIdx.x * 256;
    int ld = nb + t; if (ld >= NN) ld = NN - 1;
    sb[t] = batch[ld];
    __syncthreads();
    const int slot = t >> 4;              // 16 node-slots
    const int fl = t & 15;                // feature chunk fl*8..fl*8+7
    const int f0 = fl * 8;
    float acc[8] = {0.f, 0.f, 0.f, 0.f, 0.f, 0.f, 0.f, 0.f};
    int cur = -1;
    for (int i = slot; i < 256; i += 16) {
        int n = nb + i;
        if (n >= NN) break;
        int g = sb[i];
        if (g != cur) {
            if (cur >= 0) {
#pragma unroll
                for (int j = 0; j < 8; j++)
                    unsafeAtomicAdd(&gr[(size_t)cur * HID + f0 + j], acc[j]);
            }
#pragma unroll
            for (int j = 0; j < 8; j++) acc[j] = 0.f;
            cur = g;
        }
        ushort8v v = *(const ushort8v*)&xb[(size_t)n * HID + f0];
#pragma unroll
        for (int j = 0; j < 8; j++) acc[j] += bf2f(v[j]);
    }
    if (cur >= 0) {
#pragma unroll
        for (int j = 0; j < 8; j++)
            unsafeAtomicAdd(&gr[(size_t)cur * HID + f0 + j], acc[j]);
    }
}

// ---------------------------------------------------------------------------
// Readout: out[g] = relu(gr[g] @ W1^T + b1) @ W2^T + b2   (128 blocks x 64)
// ---------------------------------------------------------------------------
__global__ __launch_bounds__(64) void k_readout(
    const float* __restrict__ gr, const float* __restrict__ W1,
    const float* __restrict__ b1, const float* __restrict__ W2,
    const float* __restrict__ b2, float* __restrict__ out)
{
    const int g = blockIdx.x, j = threadIdx.x;
    float acc = b1[j];
    const float4* grow = (const float4*)&gr[g * HID];
    const float4* wrow = (const float4*)&W1[j * HID];
#pragma unroll
    for (int k4 = 0; k4 < 32; k4++) {
        float4 a = grow[k4], w = wrow[k4];
        acc += a.x * w.x + a.y * w.y + a.z * w.z + a.w * w.w;
    }
    float h = fmaxf(acc, 0.0f) * W2[j];
#pragma unroll
    for (int msk = 32; msk >= 1; msk >>= 1) h += __shfl_xor(h, msk);
    if (j == 0) out[g] = h + b2[0];
}

// ---------------------------------------------------------------------------
extern "C" void kernel_launch(void* const* d_in, const int* in_sizes, int n_in,
                              void* d_out, int out_size, void* d_ws, size_t ws_size,
                              hipStream_t stream)
{
    const float* nf    = (const float*)d_in[0];
    const int*   ei    = (const int*)d_in[1];
    const int*   batch = (const int*)d_in[2];
    const float* embW  = (const float*)d_in[3];
    const float* embb  = (const float*)d_in[4];
    const float* embg  = (const float*)d_in[5];
    const float* embbe = (const float*)d_in[6];
    const float* msgW  = (const float*)d_in[7];
    const float* msgb  = (const float*)d_in[8];
    const float* attW  = (const float*)d_in[9];
    const float* attb  = (const float*)d_in[10];
    const float* Wih   = (const float*)d_in[11];
    const float* bih   = (const float*)d_in[12];
    const float* Whh   = (const float*)d_in[13];
    const float* bhh   = (const float*)d_in[14];
    const float* bng   = (const float*)d_in[15];
    const float* bnb   = (const float*)d_in[16];
    const float* roW1  = (const float*)d_in[17];
    const float* rob1  = (const float*)d_in[18];
    const float* roW2  = (const float*)d_in[19];
    const float* rob2  = (const float*)d_in[20];
    const int* src = ei;
    const int* dst = ei + NE;
    float* out = (float*)d_out;

    // ---- workspace layout. Zeroed buffers (bnsum|gr|cnt) contiguous up
    //      front -> ONE memset covers all three. All sections 16B-mult. ----
    char* base = (char*)d_ws;
    const size_t NHP = (size_t)NNP * HID;    // padded rows
    float* bnsum = (float*)base;                         // 10240 B reserved
    float* gr    = (float*)(base + 10240);               // 65536 B
    int* cnt     = (int*)(base + 10240 + 65536);         // 50176*4 = 200704 B
    const size_t ZBYTES = 10240 + 65536 + 200704;        // single memset region
    unsigned short* y16   = (unsigned short*)(base + ZBYTES); // bf16 pre-BN state
    unsigned short* xb    = y16 + NHP;                        // bf16 node state
    unsigned short* aggxb = xb + NHP;                         // bf16 gather output
    float* as_   = (float*)(aggxb + NHP);    // NNP floats
    float* ad_   = as_ + NNP;
    float* sumatt= ad_ + NNP;
    float* bmih  = sumatt + NNP;             // 4*384
    int* rowptr  = (int*)(bmih + 4 * 384);   // NNP ints (need NN+1)
    int* wptr    = rowptr + NNP;             // NN
    int* bsum    = wptr + NNP;               // 128 (scan block totals)
    int* ssrc    = bsum + 128;               // NE
    unsigned short* wcb  = (unsigned short*)(ssrc + NE); // 4*49152 bf16 frags
    unsigned short* whhb = wcb + 4 * 49152;              // 4*49152 bf16 frags
    unsigned short* nfb  = whhb + 4 * 49152;             // NNP*96 bf16 padded nf
    unsigned short* web  = nfb + (size_t)NNP * 96;       // 12288 emb B-frags

    // ---- once-per-call precompute ----
    hipMemsetAsync(base, 0, ZBYTES, stream);             // bnsum + gr + cnt
    k_wc<<<4 * 384, 128, 0, stream>>>(Wih, msgW, msgb, wcb, bmih);
    k_prep<<<PREP_G, 256, 0, stream>>>(Whh, whhb, nf, nfb, embW, web);
    k_count<<<(NE + 255) / 256, 256, 0, stream>>>(dst, cnt);
    k_scan1<<<SCAN_G, SCAN_B, 0, stream>>>(cnt, rowptr, bsum);
    k_scan2<<<1, 128, 0, stream>>>(bsum, rowptr);
    k_scan3<<<SCAN_G, SCAN_B, 0, stream>>>(rowptr, bsum, wptr);
    k_scatter<<<(NE + 255) / 256, 256, 0, stream>>>(src, dst, wptr, ssrc);

    // ---- MFMA embedding (BN sums -> slot 0) + fused BN/att-proj ----
    k_embed_m<<<NB128, 512, 0, stream>>>(nfb, web, embb, y16, bnsum);
    k_bnx<<<NN / 16, 256, 0, stream>>>(y16, bnsum, embg, embbe, attW, 1, xb, as_, ad_);

    for (int l = 0; l < NLAYERS; l++) {
        k_gather<<<NN / 8, 256, 0, stream>>>(rowptr, ssrc, xb, as_, ad_, attb, l, aggxb, sumatt);
        k_gru<<<NB128, 512, 0, stream>>>(
            aggxb, sumatt, xb,
            wcb + (size_t)l * 49152, bmih + (size_t)l * 384, bih + (size_t)l * 384,
            whhb + (size_t)l * 49152, bhh + (size_t)l * 384, y16, bnsum + (l + 1) * 256);
        const int do_proj = (l + 1 < NLAYERS) ? 1 : 0;
        const float* attW_next = attW + (size_t)((l + 1 < NLAYERS) ? l + 1 : l) * 256;
        k_bnx<<<NN / 16, 256, 0, stream>>>(y16, bnsum + (l + 1) * 256,
                                           bng + (size_t)l * HID, bnb + (size_t)l * HID,
                                           attW_next, do_proj, xb, as_, ad_);
    }

    k_pool<<<(NN + 255) / 256, 256, 0, stream>>>(xb, batch, gr);
    k_readout<<<NGRAPHS, 64, 0, stream>>>(gr, roW1, rob1, roW2, rob2, out);
}

// Round 17
// 564.059 us; speedup vs baseline: 1.0102x; 1.0102x over previous
//
#include <hip/hip_runtime.h>
#include <math.h>

#define NN 50000
#define NE 600000
#define ADIM 75
#define HID 128
#define NLAYERS 4
#define NGRAPHS 128
#define BN_EPS 1e-5f
#define NNP 50048   // NN padded to 128-node blocks (50048 = 391*128)
#define NB128 (NNP / 128)   // 391 node-blocks

typedef short bhalf8 __attribute__((ext_vector_type(8)));
typedef unsigned short ushort8v __attribute__((ext_vector_type(8)));
typedef float floatx4 __attribute__((ext_vector_type(4)));

__device__ __forceinline__ float sigm(float v) { return 1.0f / (1.0f + __expf(-v)); }
__device__ __forceinline__ float tanh_f(float v) {
    return 1.0f - 2.0f / (__expf(2.0f * v) + 1.0f);
}

// fp32 -> bf16 with round-to-nearest-even
__device__ __forceinline__ unsigned short f2bf(float f) {
    unsigned u = __builtin_bit_cast(unsigned, f);
    u = (u + 0x7FFFu + ((u >> 16) & 1u)) >> 16;
    return (unsigned short)u;
}
__device__ __forceinline__ float bf2f(unsigned short h) {
    return __builtin_bit_cast(float, ((unsigned)h) << 16);
}

// async global->LDS, 16B per lane. LDS dest is wave-uniform base + lane*16;
// global src is per-lane (must already include +lane*16).
__device__ __forceinline__ void gl2lds16(const void* g, void* l) {
    __builtin_amdgcn_global_load_lds(
        (const __attribute__((address_space(1))) unsigned int*)g,
        (__attribute__((address_space(3))) unsigned int*)l, 16, 0, 0);
}

// ---------------------------------------------------------------------------
// k_prep: merged precompute (range-split by blockIdx):
//   [0,768):      Whh -> whhb bf16 MFMA B-fragments
//   [768,5456):   nf [NN x 75] fp32 -> nfb [NNP x 96] bf16 (K zero-padded)
//   [5456,5504):  embW [128 x 75] -> web bf16 B-frags (K padded 75->96)
// ---------------------------------------------------------------------------
#define PREP_G (768 + 4688 + 48)
__global__ __launch_bounds__(256) void k_prep(
    const float* __restrict__ Whh, unsigned short* __restrict__ whhb,
    const float* __restrict__ nf, unsigned short* __restrict__ nfb,
    const float* __restrict__ W, unsigned short* __restrict__ web)
{
    const int b = blockIdx.x;
    if (b < 768) {
        int e = b * 256 + threadIdx.x;           // < 196608 = 4*49152
        int l = e / 49152, em = e - l * 49152;
        int j = em & 7, n = (em >> 3) & 15, quad = (em >> 7) & 3;
        int kb = (em >> 9) & 3, tc = (em >> 11) & 7, g = (em >> 14);
        int row = g * 128 + tc * 16 + n;
        int kk = kb * 32 + quad * 8 + j;
        whhb[e] = f2bf(Whh[(size_t)l * 49152 + row * 128 + kk]);
    } else if (b < 768 + 4688) {
        int e = (b - 768) * 256 + threadIdx.x;   // (n, k4): 50000*24
        if (e >= NN * 24) return;
        int n = e / 24, k4 = e - n * 24;
        ushort4 o;
        int k = k4 * 4;
        o.x = (k + 0 < ADIM) ? f2bf(nf[(size_t)n * ADIM + k + 0]) : 0;
        o.y = (k + 1 < ADIM) ? f2bf(nf[(size_t)n * ADIM + k + 1]) : 0;
        o.z = (k + 2 < ADIM) ? f2bf(nf[(size_t)n * ADIM + k + 2]) : 0;
        o.w = (k + 3 < ADIM) ? f2bf(nf[(size_t)n * ADIM + k + 3]) : 0;
        ((ushort4*)nfb)[(size_t)n * 24 + k4] = o;
    } else {
        int e = (b - 5456) * 256 + threadIdx.x;  // 0..12287
        int j = e & 7, n = (e >> 3) & 15, quad = (e >> 7) & 3;
        int kb = (e >> 9) % 3, tc = e / 1536;
        int row = tc * 16 + n;
        int kk = kb * 32 + quad * 8 + j;
        web[e] = (kk < ADIM) ? f2bf(W[row * ADIM + kk]) : 0;
    }
}

// ---------------------------------------------------------------------------
// MFMA embedding — 512 threads (8 waves), 128 nodes/block, grid 391.
// y stored as BF16 (y16); BN partials from rounded value.
// ---------------------------------------------------------------------------
__global__ __launch_bounds__(512) void k_embed_m(
    const unsigned short* __restrict__ nfb, const unsigned short* __restrict__ web,
    const float* __restrict__ b, unsigned short* __restrict__ y16,
    float* __restrict__ bnsum)
{
    __shared__ __align__(16) unsigned short wbe[12288];    // 24 KB emb B-frags
    __shared__ float sred[1024], sred2[1024];              // 8 KB BN partials
    const int t = threadIdx.x;
    const int wave = t >> 6, lane = t & 63;
    const int col = lane & 15, quad = (lane >> 4) & 3;
    const int node0 = blockIdx.x * 128;

    // stage web: 24576 B = 8 waves x 3 KB, identity copy
    {
        const char* gsrc = (const char*)web + wave * 3072 + lane * 16;
        char* ldst = (char*)wbe + wave * 3072;
#pragma unroll
        for (int i = 0; i < 3; i++)
            gl2lds16(gsrc + i * 1024, ldst + i * 1024);
    }

    const int anode = node0 + wave * 16 + col;
    bhalf8 afN[3];
#pragma unroll
    for (int kb = 0; kb < 3; kb++)
        afN[kb] = *(const bhalf8*)&nfb[(size_t)anode * 96 + kb * 32 + quad * 8];

    floatx4 acc[8];
#pragma unroll
    for (int tc = 0; tc < 8; tc++) {
        float bv = b[tc * 16 + col];
        acc[tc] = (floatx4){bv, bv, bv, bv};
    }
    __syncthreads();   // drains vmcnt -> wbe staged

#pragma unroll
    for (int tc = 0; tc < 8; tc++) {
        bhalf8 bfr[3];
#pragma unroll
        for (int kb = 0; kb < 3; kb++)
            bfr[kb] = *(const bhalf8*)&wbe[((tc * 3 + kb) * 64 + lane) * 8];
#pragma unroll
        for (int kb = 0; kb < 3; kb++)
            acc[tc] = __builtin_amdgcn_mfma_f32_16x16x32_bf16(afN[kb], bfr[kb], acc[tc], 0, 0, 0);
    }

    // relu + bf16 y stores + register BN partials (from rounded value)
    float ps[8], ps2[8];
#pragma unroll
    for (int tc = 0; tc < 8; tc++) {
        ps[tc] = 0.f; ps2[tc] = 0.f;
#pragma unroll
        for (int e = 0; e < 4; e++) {
            float v = fmaxf(acc[tc][e], 0.0f);
            int nd = node0 + wave * 16 + quad * 4 + e;
            if (nd < NN) {
                unsigned short vb = f2bf(v);
                float vr = bf2f(vb);
                y16[(size_t)nd * HID + tc * 16 + col] = vb;
                ps[tc] += vr; ps2[tc] += vr * vr;
            }
        }
    }
#pragma unroll
    for (int tc = 0; tc < 8; tc++) {
        ps[tc]  += __shfl_xor(ps[tc], 16);  ps2[tc] += __shfl_xor(ps2[tc], 16);
        ps[tc]  += __shfl_xor(ps[tc], 32);  ps2[tc] += __shfl_xor(ps2[tc], 32);
    }
    if (quad == 0) {
#pragma unroll
        for (int tc = 0; tc < 8; tc++) {
            sred[wave * 128 + tc * 16 + col]  = ps[tc];
            sred2[wave * 128 + tc * 16 + col] = ps2[tc];
        }
    }
    __syncthreads();
    if (t < 128) {
        float s = 0.f, s2 = 0.f;
#pragma unroll
        for (int w = 0; w < 8; w++) { s += sred[w * 128 + t]; s2 += sred2[w * 128 + t]; }
        unsafeAtomicAdd(&bnsum[t], s);
        unsafeAtomicAdd(&bnsum[128 + t], s2);
    }
}

// ---------------------------------------------------------------------------
// Fused BN-finalize + BN-apply + bf16 mirror + attention projections.
// R27: vectorized 16 B/lane; 16 lanes/node, 16 nodes/block, grid 3125.
// ---------------------------------------------------------------------------
__global__ __launch_bounds__(256) void k_bnx(
    const unsigned short* __restrict__ y16, const float* __restrict__ bnsum,
    const float* __restrict__ g, const float* __restrict__ beta,
    const float* __restrict__ attW, int do_proj,
    unsigned short* __restrict__ xb,
    float* __restrict__ as_, float* __restrict__ ad_)
{
    const int t = threadIdx.x;
    const int n = blockIdx.x * 16 + (t >> 4);   // 16 nodes/block (3125*16=NN)
    const int fl = t & 15;                      // feature chunk fl*8..fl*8+7
    const int f0 = fl * 8;
    const float inv = 1.0f / (float)NN;

    // per-lane BN scale/shift for 8 features (all inputs L2-resident)
    float sc[8], sh[8];
#pragma unroll
    for (int j4 = 0; j4 < 2; j4++) {
        float4 s  = *(const float4*)&bnsum[f0 + j4 * 4];
        float4 s2 = *(const float4*)&bnsum[128 + f0 + j4 * 4];
        float4 gg = *(const float4*)&g[f0 + j4 * 4];
        float4 bb = *(const float4*)&beta[f0 + j4 * 4];
        const float* sp = (const float*)&s;
        const float* s2p = (const float*)&s2;
        const float* gp = (const float*)&gg;
        const float* bp = (const float*)&bb;
#pragma unroll
        for (int j = 0; j < 4; j++) {
            float m = sp[j] * inv;
            float vv = s2p[j] * inv - m * m;
            float scv = gp[j] * rsqrtf(vv + BN_EPS);
            sc[j4 * 4 + j] = scv;
            sh[j4 * 4 + j] = bp[j] - m * scv;
        }
    }

    ushort8v yv = *(const ushort8v*)&y16[(size_t)n * HID + f0];
    float xv[8];
    ushort8v o;
#pragma unroll
    for (int j = 0; j < 8; j++) {
        xv[j] = bf2f(yv[j]) * sc[j] + sh[j];
        o[j] = f2bf(xv[j]);
    }
    *(ushort8v*)&xb[(size_t)n * HID + f0] = o;

    if (do_proj) {
        float pas = 0.f, pad = 0.f;
#pragma unroll
        for (int j4 = 0; j4 < 2; j4++) {
            float4 ws = *(const float4*)&attW[f0 + j4 * 4];
            float4 wd = *(const float4*)&attW[128 + f0 + j4 * 4];
            const float* wsp = (const float*)&ws;
            const float* wdp = (const float*)&wd;
#pragma unroll
            for (int j = 0; j < 4; j++) {
                pas += xv[j4 * 4 + j] * wsp[j];
                pad += xv[j4 * 4 + j] * wdp[j];
            }
        }
#pragma unroll
        for (int msk = 8; msk >= 1; msk >>= 1) {
            pas += __shfl_xor(pas, msk);
            pad += __shfl_xor(pad, msk);
        }
        if (fl == 0) { as_[n] = pas; ad_[n] = pad; }
    }
}

// ---------------------------------------------------------------------------
// Combined-weight precompute + DIRECT fragment write (each block owns one
// full row of Wc = Wih[l] @ Wm[l] -> emits that row's bf16 MFMA B-frags;
// fp32 Wc never materialized). Also bmih[l] = Wih[l] @ bm[l].
// ---------------------------------------------------------------------------
__global__ __launch_bounds__(128) void k_wc(
    const float* __restrict__ Wih, const float* __restrict__ Wm,
    const float* __restrict__ bm, unsigned short* __restrict__ wcb,
    float* __restrict__ bmih)
{
    __shared__ float sw[128];
    __shared__ float red[128];
    const int b = blockIdx.x;
    const int l = b / 384, r = b - l * 384;      // r = row within 384x128
    const int t = threadIdx.x;
    const float* wihrow = Wih + ((size_t)l * 384 + r) * 128;
    sw[t] = wihrow[t];
    __syncthreads();
    const float* wm = Wm + (size_t)l * 128 * 128;
    float acc = 0.f;
#pragma unroll 8
    for (int k = 0; k < 128; k++) acc += sw[k] * wm[k * 128 + t];
    // fragment write: row -> (g,tc,n), col t -> (kb,quad,j)
    {
        int g = r >> 7, rowin = r & 127;
        int tc = rowin >> 4, n = rowin & 15;
        int kb = t >> 5, quad = (t >> 3) & 3, j = t & 7;
        wcb[(size_t)l * 49152 + (g << 14) + (tc << 11) + (kb << 9) +
            (quad << 7) + (n << 3) + j] = f2bf(acc);
    }
    red[t] = sw[t] * bm[l * 128 + t];
    __syncthreads();
#pragma unroll
    for (int off = 64; off >= 1; off >>= 1) {
        if (t < off) red[t] += red[t + off];
        __syncthreads();
    }
    if (t == 0) bmih[l * 384 + r] = red[0];
}

// ---------------------------------------------------------------------------
// CSR build: histogram, 3-kernel device-wide scan, scatter
// ---------------------------------------------------------------------------
__global__ __launch_bounds__(256) void k_count(const int* __restrict__ dst, int* __restrict__ cnt)
{
    int e = blockIdx.x * 256 + threadIdx.x;
    if (e < NE) atomicAdd(&cnt[dst[e]], 1);
}

#define SCAN_B 512
#define SCAN_G 98          // 98*512 = 50176 >= 50000

__global__ __launch_bounds__(SCAN_B) void k_scan1(
    const int* __restrict__ cnt, int* __restrict__ rowptr, int* __restrict__ bsum)
{
    __shared__ int s[SCAN_B];
    const int t = threadIdx.x;
    const int i = blockIdx.x * SCAN_B + t;
    int v = (i < NN) ? cnt[i] : 0;
    s[t] = v;
    __syncthreads();
#pragma unroll
    for (int off = 1; off < SCAN_B; off <<= 1) {
        int u = (t >= off) ? s[t - off] : 0;
        __syncthreads();
        s[t] += u;
        __syncthreads();
    }
    if (i < NN) rowptr[i] = s[t] - v;        // local exclusive
    if (t == SCAN_B - 1) bsum[blockIdx.x] = s[t];
}

__global__ __launch_bounds__(128) void k_scan2(int* __restrict__ bsum, int* __restrict__ rowptr)
{
    __shared__ int s[128];
    const int t = threadIdx.x;
    int v = (t < SCAN_G) ? bsum[t] : 0;
    s[t] = v;
    __syncthreads();
#pragma unroll
    for (int off = 1; off < 128; off <<= 1) {
        int u = (t >= off) ? s[t - off] : 0;
        __syncthreads();
        s[t] += u;
        __syncthreads();
    }
    if (t < SCAN_G) bsum[t] = s[t] - v;      // exclusive offsets
    if (t == 127) rowptr[NN] = s[127];       // grand total (= NE)
}

__global__ __launch_bounds__(SCAN_B) void k_scan3(
    int* __restrict__ rowptr, const int* __restrict__ bsum, int* __restrict__ wptr)
{
    const int i = blockIdx.x * SCAN_B + threadIdx.x;
    if (i < NN) {
        int v = rowptr[i] + bsum[blockIdx.x];
        rowptr[i] = v;
        wptr[i] = v;
    }
}

__global__ __launch_bounds__(256) void k_scatter(
    const int* __restrict__ src, const int* __restrict__ dst,
    int* __restrict__ wptr, int* __restrict__ ssrc)
{
    int e = blockIdx.x * 256 + threadIdx.x;
    if (e < NE) {
        int d = dst[e];
        int pos = atomicAdd(&wptr[d], 1);
        ssrc[pos] = src[e];
    }
}

// ---------------------------------------------------------------------------
// Gather-aggregate — R28: row-load pipelining on R26's 16 B/lane form.
// ids prefetched one batch ahead; row loads one batch ahead; ~1 serial
// load-drain per node at deg~12. VGPR ~100 (same occupancy bucket).
// R22: own high-TLP geometry (6250 blocks). R24: don't grow live state.
// ---------------------------------------------------------------------------
__global__ __launch_bounds__(256) void k_gather(
    const int* __restrict__ rowptr, const int* __restrict__ ssrc,
    const unsigned short* __restrict__ xb, const float* __restrict__ as_,
    const float* __restrict__ ad_, const float* __restrict__ attb, int l,
    unsigned short* __restrict__ aggxb, float* __restrict__ sumatt)
{
    const int t = threadIdx.x;
    const int n = blockIdx.x * 8 + (t >> 5);
    const int lane32 = t & 31;
    const int sub = lane32 >> 4;          // which half of the edge batch
    const int fl = lane32 & 15;           // feature chunk: fl*8 .. fl*8+7
    const int r0 = rowptr[n], r1 = rowptr[n + 1];
    const float adv = ad_[n] + attb[l];
    float acc[8] = {0.f, 0.f, 0.f, 0.f, 0.f, 0.f, 0.f, 0.f};
    float satt = 0.f;

    int idsB[8];                          // ids for batch k+1 (arrived)
    ushort8v vA[4]; float aA[4];          // rows for batch k (in flight/arrived)
    if (r0 < r1) {
        int idsA[8];
#pragma unroll
        for (int k = 0; k < 8; k++) {
            int i0 = r0 + k;     if (i0 >= r1) i0 = r1 - 1;
            int i1 = r0 + 8 + k; if (i1 >= r1) i1 = r1 - 1;
            idsA[k] = ssrc[i0];
            idsB[k] = ssrc[i1];
        }
#pragma unroll
        for (int k = 0; k < 4; k++) {
            const int e = k * 2 + sub;
            vA[k] = *(const ushort8v*)&xb[(size_t)idsA[e] * 128 + fl * 8];
            aA[k] = as_[idsA[e]];
        }
    }
    for (int base = r0; base < r1; base += 8) {
        int idsN[8];                      // prefetch ids for batch k+2
        if (base + 16 < r1) {
#pragma unroll
            for (int k = 0; k < 8; k++) {
                int idx = base + 16 + k; if (idx >= r1) idx = r1 - 1;
                idsN[k] = ssrc[idx];
            }
        }
        ushort8v vN[4]; float aN[4];      // issue rows for batch k+1
        if (base + 8 < r1) {
#pragma unroll
            for (int k = 0; k < 4; k++) {
                const int e = k * 2 + sub;
                vN[k] = *(const ushort8v*)&xb[(size_t)idsB[e] * 128 + fl * 8];
                aN[k] = as_[idsB[e]];
            }
        }
        // accumulate batch k (vA/aA already in flight since previous iter)
#pragma unroll
        for (int k = 0; k < 4; k++) {
            const int e = k * 2 + sub;
            if (base + e < r1) {
                float att = sigm(aA[k] + adv);
#pragma unroll
                for (int j = 0; j < 8; j++)
                    acc[j] += bf2f(vA[k][j]) * att;
                if (fl == 0) satt += att;
            }
        }
        // rotate
#pragma unroll
        for (int k = 0; k < 4; k++) { vA[k] = vN[k]; aA[k] = aN[k]; }
#pragma unroll
        for (int k = 0; k < 8; k++) idsB[k] = idsN[k];
    }
    // combine the two edge-subgroups (lane ^ 16 stays within the node group)
#pragma unroll
    for (int j = 0; j < 8; j++) acc[j] += __shfl_xor(acc[j], 16);
    satt += __shfl_xor(satt, 16);
    if (lane32 < 16) {
        ushort8v o;
#pragma unroll
        for (int j = 0; j < 8; j++) o[j] = f2bf(acc[j]);
        *(ushort8v*)&aggxb[(size_t)n * 128 + fl * 8] = o;
    }
    if (lane32 == 0) sumatt[n] = satt;
}

// ---------------------------------------------------------------------------
// MFMA GRU — R20 geometry (512 thr / 8 waves, 128 nodes/block, grid 391).
// R30: REVERTED R29's LDS-staged epilogue — it introduced 200k LDS bank
// conflicts (scalar ushort reads at 256 B row stride = 4-way quad-group
// conflict, Guideline-4 trap) + an extra barrier, net +1.6 us. The
// scattered global xv loads it replaced were already hidden. k_gru's
// ~49.4 us is its structural floor in this decomposition: R16-R24
// exhausted schedule/occupancy/traffic, R29 exhausted the epilogue.
// R19: no extra node-tiles/wave. R22: no gather fusion. R11/R13: no
// occupancy forcing. R8: no column split.
// ---------------------------------------------------------------------------
#define STAGE_W(SRC)                                                          \
    {                                                                         \
        const char* gsrc = (const char*)(SRC) + wave * 4096 + lane * 16;      \
        char* ldst = (char*)wbuf + wave * 4096;                               \
        _Pragma("unroll")                                                     \
        for (int i = 0; i < 4; i++)                                           \
            gl2lds16(gsrc + i * 1024, ldst + i * 1024);                       \
    }

#define MMGL(AF, ACC)                                                         \
    _Pragma("unroll")                                                         \
    for (int tc = 0; tc < 8; tc++) {                                          \
        bhalf8 bfr[4];                                                        \
        _Pragma("unroll")                                                     \
        for (int kb = 0; kb < 4; kb++)                                        \
            bfr[kb] = *(const bhalf8*)&wbuf[((tc * 4 + kb) * 64 + lane) * 8]; \
        _Pragma("unroll")                                                     \
        for (int kb = 0; kb < 4; kb++)                                        \
            ACC[tc] = __builtin_amdgcn_mfma_f32_16x16x32_bf16(AF[kb], bfr[kb], ACC[tc], 0, 0, 0); \
    }

__global__ __launch_bounds__(512) void k_gru(
    const unsigned short* __restrict__ aggxb, const float* __restrict__ sumatt,
    const unsigned short* __restrict__ xb,
    const unsigned short* __restrict__ wcb, const float* __restrict__ bmih,
    const float* __restrict__ bih,
    const unsigned short* __restrict__ whhb, const float* __restrict__ bhh,
    unsigned short* __restrict__ y16, float* __restrict__ bnsum)
{
    __shared__ __align__(16) unsigned short wbuf[16384];   // 32 KB weight stage
    __shared__ float sred[1024], sred2[1024];              // 8 KB BN partials
    const int t = threadIdx.x;
    const int wave = t >> 6, lane = t & 63;
    const int col = lane & 15, quad = (lane >> 4) & 3;
    const int node0 = blockIdx.x * 128;

    STAGE_W(wcb + 0 * 16384);    // issue gate-r Wc stage before A loads

    const int anode = node0 + wave * 16 + col;
    bhalf8 afA[4], afX[4];
#pragma unroll
    for (int kb = 0; kb < 4; kb++) {
        afA[kb] = *(const bhalf8*)&aggxb[(size_t)anode * HID + kb * 32 + quad * 8];
        afX[kb] = *(const bhalf8*)&xb[(size_t)anode * HID + kb * 32 + quad * 8];
    }
    float sa[4];
#pragma unroll
    for (int e = 0; e < 4; e++) sa[e] = sumatt[node0 + wave * 16 + quad * 4 + e];

    floatx4 accR[8], accN[8];

    // ===== gate r: merged accumulator (gi+gh) =====
#pragma unroll
    for (int tc = 0; tc < 8; tc++) {
        int f = 0 * 128 + tc * 16 + col;
        float b0 = bih[f] + bhh[f], bm = bmih[f];
        accR[tc] = (floatx4){b0 + sa[0] * bm, b0 + sa[1] * bm, b0 + sa[2] * bm, b0 + sa[3] * bm};
    }
    __syncthreads();                 // wcb[r] staged (drains vmcnt)
    MMGL(afA, accR);
    __syncthreads();                 // all waves done reading
    STAGE_W(whhb + 0 * 16384);
    __syncthreads();
    MMGL(afX, accR);
    __syncthreads();
    STAGE_W(whhb + 2 * 16384);       // prefetch gate-n Whh; sigm overlaps
#pragma unroll
    for (int tc = 0; tc < 8; tc++)
#pragma unroll
        for (int e = 0; e < 4; e++)
            accR[tc][e] = sigm(accR[tc][e]);          // accR now holds r

    // ===== gate n: acc = afX@Whh + bh; acc = r*acc + bi + sa*bm; acc += afA@Wc =====
#pragma unroll
    for (int tc = 0; tc < 8; tc++) {
        float bh = bhh[2 * 128 + tc * 16 + col];
        accN[tc] = (floatx4){bh, bh, bh, bh};
    }
    __syncthreads();
    MMGL(afX, accN);
    __syncthreads();
    STAGE_W(wcb + 2 * 16384);        // prefetch gate-n Wc; r-merge overlaps
#pragma unroll
    for (int tc = 0; tc < 8; tc++) {
        int f = 2 * 128 + tc * 16 + col;
        float bi = bih[f], bm = bmih[f];
#pragma unroll
        for (int e = 0; e < 4; e++)
            accN[tc][e] = accR[tc][e] * accN[tc][e] + bi + sa[e] * bm;
    }
    __syncthreads();
    MMGL(afA, accN);
    __syncthreads();
    STAGE_W(wcb + 1 * 16384);        // prefetch gate-z Wc; tanh overlaps
#pragma unroll
    for (int tc = 0; tc < 8; tc++)
#pragma unroll
        for (int e = 0; e < 4; e++)
            accN[tc][e] = tanh_f(accN[tc][e]);        // accN now holds n

    // ===== gate z: merged accumulator (reuse accR) =====
#pragma unroll
    for (int tc = 0; tc < 8; tc++) {
        int f = 1 * 128 + tc * 16 + col;
        float b0 = bih[f] + bhh[f], bm = bmih[f];
        accR[tc] = (floatx4){b0 + sa[0] * bm, b0 + sa[1] * bm, b0 + sa[2] * bm, b0 + sa[3] * bm};
    }
    __syncthreads();
    MMGL(afA, accR);
    __syncthreads();
    STAGE_W(whhb + 1 * 16384);
    __syncthreads();
    MMGL(afX, accR);

    // ===== h = (1-z)*n + z*x; bf16 y stores; BN partials from rounded h =====
    float ps[8], ps2[8];
#pragma unroll
    for (int tc = 0; tc < 8; tc++) {
        ps[tc] = 0.f; ps2[tc] = 0.f;
#pragma unroll
        for (int e = 0; e < 4; e++) {
            float z = sigm(accR[tc][e]);
            int nd = node0 + wave * 16 + quad * 4 + e;
            float xv = bf2f(xb[(size_t)nd * HID + tc * 16 + col]);
            float h = (1.0f - z) * accN[tc][e] + z * xv;
            if (nd < NN) {
                unsigned short hb = f2bf(h);
                float hr = bf2f(hb);
                y16[(size_t)nd * HID + tc * 16 + col] = hb;
                ps[tc] += hr; ps2[tc] += hr * hr;
            }
        }
    }
#pragma unroll
    for (int tc = 0; tc < 8; tc++) {
        ps[tc]  += __shfl_xor(ps[tc], 16);  ps2[tc] += __shfl_xor(ps2[tc], 16);
        ps[tc]  += __shfl_xor(ps[tc], 32);  ps2[tc] += __shfl_xor(ps2[tc], 32);
    }
    if (quad == 0) {
#pragma unroll
        for (int tc = 0; tc < 8; tc++) {
            sred[wave * 128 + tc * 16 + col]  = ps[tc];
            sred2[wave * 128 + tc * 16 + col] = ps2[tc];
        }
    }
    __syncthreads();
    if (t < 128) {
        float s = 0.f, s2 = 0.f;
#pragma unroll
        for (int w = 0; w < 8; w++) { s += sred[w * 128 + t]; s2 += sred2[w * 128 + t]; }
        unsafeAtomicAdd(&bnsum[t], s);
        unsafeAtomicAdd(&bnsum[128 + t], s2);
    }
}

// ---------------------------------------------------------------------------
// Segmented sum-pool over bf16 xb (batch_idx is SORTED).
// R28: vectorized 16 B/lane; 16 node-slots x 16 feature-chunks per block.
// ---------------------------------------------------------------------------
__global__ __launch_bounds__(256) void k_pool(
    const unsigned short* __restrict__ xb, const int* __restrict__ batch,
    float* __restrict__ gr)
{
    __shared__ int sb[256];
    const int t = threadIdx.x;
    const int nb = blockIdx.x * 256;
    int ld = nb + t; if (ld >= NN) ld = NN - 1;
    sb[t] = batch[ld];
    __syncthreads();
    const int slot = t >> 4;              // 16 node-slots
    const int fl = t & 15;                // feature chunk fl*8..fl*8+7
    const int f0 = fl * 8;
    float acc[8] = {0.f, 0.f, 0.f, 0.f, 0.f, 0.f, 0.f, 0.f};
    int cur = -1;
    for (int i = slot; i < 256; i += 16) {
        int n = nb + i;
        if (n >= NN) break;
        int g = sb[i];
        if (g != cur) {
            if (cur >= 0) {
#pragma unroll
                for (int j = 0; j < 8; j++)
                    unsafeAtomicAdd(&gr[(size_t)cur * HID + f0 + j], acc[j]);
            }
#pragma unroll
            for (int j = 0; j < 8; j++) acc[j] = 0.f;
            cur = g;
        }
        ushort8v v = *(const ushort8v*)&xb[(size_t)n * HID + f0];
#pragma unroll
        for (int j = 0; j < 8; j++) acc[j] += bf2f(v[j]);
    }
    if (cur >= 0) {
#pragma unroll
        for (int j = 0; j < 8; j++)
            unsafeAtomicAdd(&gr[(size_t)cur * HID + f0 + j], acc[j]);
    }
}

// ---------------------------------------------------------------------------
// Readout: out[g] = relu(gr[g] @ W1^T + b1) @ W2^T + b2   (128 blocks x 64)
// ---------------------------------------------------------------------------
__global__ __launch_bounds__(64) void k_readout(
    const float* __restrict__ gr, const float* __restrict__ W1,
    const float* __restrict__ b1, const float* __restrict__ W2,
    const float* __restrict__ b2, float* __restrict__ out)
{
    const int g = blockIdx.x, j = threadIdx.x;
    float acc = b1[j];
    const float4* grow = (const float4*)&gr[g * HID];
    const float4* wrow = (const float4*)&W1[j * HID];
#pragma unroll
    for (int k4 = 0; k4 < 32; k4++) {
        float4 a = grow[k4], w = wrow[k4];
        acc += a.x * w.x + a.y * w.y + a.z * w.z + a.w * w.w;
    }
    float h = fmaxf(acc, 0.0f) * W2[j];
#pragma unroll
    for (int msk = 32; msk >= 1; msk >>= 1) h += __shfl_xor(h, msk);
    if (j == 0) out[g] = h + b2[0];
}

// ---------------------------------------------------------------------------
extern "C" void kernel_launch(void* const* d_in, const int* in_sizes, int n_in,
                              void* d_out, int out_size, void* d_ws, size_t ws_size,
                              hipStream_t stream)
{
    const float* nf    = (const float*)d_in[0];
    const int*   ei    = (const int*)d_in[1];
    const int*   batch = (const int*)d_in[2];
    const float* embW  = (const float*)d_in[3];
    const float* embb  = (const float*)d_in[4];
    const float* embg  = (const float*)d_in[5];
    const float* embbe = (const float*)d_in[6];
    const float* msgW  = (const float*)d_in[7];
    const float* msgb  = (const float*)d_in[8];
    const float* attW  = (const float*)d_in[9];
    const float* attb  = (const float*)d_in[10];
    const float* Wih   = (const float*)d_in[11];
    const float* bih   = (const float*)d_in[12];
    const float* Whh   = (const float*)d_in[13];
    const float* bhh   = (const float*)d_in[14];
    const float* bng   = (const float*)d_in[15];
    const float* bnb   = (const float*)d_in[16];
    const float* roW1  = (const float*)d_in[17];
    const float* rob1  = (const float*)d_in[18];
    const float* roW2  = (const float*)d_in[19];
    const float* rob2  = (const float*)d_in[20];
    const int* src = ei;
    const int* dst = ei + NE;
    float* out = (float*)d_out;

    // ---- workspace layout. Zeroed buffers (bnsum|gr|cnt) contiguous up
    //      front -> ONE memset covers all three. All sections 16B-mult. ----
    char* base = (char*)d_ws;
    const size_t NHP = (size_t)NNP * HID;    // padded rows
    float* bnsum = (float*)base;                         // 10240 B reserved
    float* gr    = (float*)(base + 10240);               // 65536 B
    int* cnt     = (int*)(base + 10240 + 65536);         // 50176*4 = 200704 B
    const size_t ZBYTES = 10240 + 65536 + 200704;        // single memset region
    unsigned short* y16   = (unsigned short*)(base + ZBYTES); // bf16 pre-BN state
    unsigned short* xb    = y16 + NHP;                        // bf16 node state
    unsigned short* aggxb = xb + NHP;                         // bf16 gather output
    float* as_   = (float*)(aggxb + NHP);    // NNP floats
    float* ad_   = as_ + NNP;
    float* sumatt= ad_ + NNP;
    float* bmih  = sumatt + NNP;             // 4*384
    int* rowptr  = (int*)(bmih + 4 * 384);   // NNP ints (need NN+1)
    int* wptr    = rowptr + NNP;             // NN
    int* bsum    = wptr + NNP;               // 128 (scan block totals)
    int* ssrc    = bsum + 128;               // NE
    unsigned short* wcb  = (unsigned short*)(ssrc + NE); // 4*49152 bf16 frags
    unsigned short* whhb = wcb + 4 * 49152;              // 4*49152 bf16 frags
    unsigned short* nfb  = whhb + 4 * 49152;             // NNP*96 bf16 padded nf
    unsigned short* web  = nfb + (size_t)NNP * 96;       // 12288 emb B-frags

    // ---- once-per-call precompute ----
    hipMemsetAsync(base, 0, ZBYTES, stream);             // bnsum + gr + cnt
    k_wc<<<4 * 384, 128, 0, stream>>>(Wih, msgW, msgb, wcb, bmih);
    k_prep<<<PREP_G, 256, 0, stream>>>(Whh, whhb, nf, nfb, embW, web);
    k_count<<<(NE + 255) / 256, 256, 0, stream>>>(dst, cnt);
    k_scan1<<<SCAN_G, SCAN_B, 0, stream>>>(cnt, rowptr, bsum);
    k_scan2<<<1, 128, 0, stream>>>(bsum, rowptr);
    k_scan3<<<SCAN_G, SCAN_B, 0, stream>>>(rowptr, bsum, wptr);
    k_scatter<<<(NE + 255) / 256, 256, 0, stream>>>(src, dst, wptr, ssrc);

    // ---- MFMA embedding (BN sums -> slot 0) + fused BN/att-proj ----
    k_embed_m<<<NB128, 512, 0, stream>>>(nfb, web, embb, y16, bnsum);
    k_bnx<<<NN / 16, 256, 0, stream>>>(y16, bnsum, embg, embbe, attW, 1, xb, as_, ad_);

    for (int l = 0; l < NLAYERS; l++) {
        k_gather<<<NN / 8, 256, 0, stream>>>(rowptr, ssrc, xb, as_, ad_, attb, l, aggxb, sumatt);
        k_gru<<<NB128, 512, 0, stream>>>(
            aggxb, sumatt, xb,
            wcb + (size_t)l * 49152, bmih + (size_t)l * 384, bih + (size_t)l * 384,
            whhb + (size_t)l * 49152, bhh + (size_t)l * 384, y16, bnsum + (l + 1) * 256);
        const int do_proj = (l + 1 < NLAYERS) ? 1 : 0;
        const float* attW_next = attW + (size_t)((l + 1 < NLAYERS) ? l + 1 : l) * 256;
        k_bnx<<<NN / 16, 256, 0, stream>>>(y16, bnsum + (l + 1) * 256,
                                           bng + (size_t)l * HID, bnb + (size_t)l * HID,
                                           attW_next, do_proj, xb, as_, ad_);
    }

    k_pool<<<(NN + 255) / 256, 256, 0, stream>>>(xb, batch, gr);
    k_readout<<<NGRAPHS, 64, 0, stream>>>(gr, roW1, rob1, roW2, rob2, out);
}